// Round 5
// baseline (533.239 us; speedup 1.0000x reference)
//
#include <hip/hip_runtime.h>

#define NSEQ  1024
#define NHEAD 12
#define HDIM  64
#define CDIM  768
#define BATCH 8

typedef short bf16x8 __attribute__((ext_vector_type(8)));
typedef float f32x4  __attribute__((ext_vector_type(4)));

__device__ __forceinline__ float bf2f(unsigned short h) {
  unsigned u = ((unsigned)h) << 16;
  float f;
  __builtin_memcpy(&f, &u, 4);
  return f;
}
__device__ __forceinline__ unsigned short f2bf(float f) {
  unsigned u;
  __builtin_memcpy(&u, &f, 4);
  u = (u + 0x7fffu + ((u >> 16) & 1u)) >> 16;
  return (unsigned short)u;
}

// async global->LDS, 16B per lane; data lands at ldsbase + lane*16
#define GLD16(GP, LP) __builtin_amdgcn_global_load_lds( \
    (const __attribute__((address_space(1))) void*)(GP), \
    (__attribute__((address_space(3))) void*)(LP), 16, 0, 0)

// ---------------- fp32 -> bf16 hi/lo conversion pre-pass ----------------
__global__ __launch_bounds__(256)
void convert_kernel(const float* __restrict__ x, const float* __restrict__ w_in,
                    const float* __restrict__ w_out,
                    unsigned short* __restrict__ xh, unsigned short* __restrict__ xl,
                    unsigned short* __restrict__ wih, unsigned short* __restrict__ wil,
                    unsigned short* __restrict__ woh)
{
  const int idx = (blockIdx.x * 256 + threadIdx.x) * 4;
  if (idx < 6291456) {
    float4 v = *(const float4*)(x + idx);
    ushort4 h, l;
    h.x = f2bf(v.x); l.x = f2bf(v.x - bf2f(h.x));
    h.y = f2bf(v.y); l.y = f2bf(v.y - bf2f(h.y));
    h.z = f2bf(v.z); l.z = f2bf(v.z - bf2f(h.z));
    h.w = f2bf(v.w); l.w = f2bf(v.w - bf2f(h.w));
    *(ushort4*)(xh + idx) = h;
    *(ushort4*)(xl + idx) = l;
  } else if (idx < 6291456 + 1769472) {
    const int j = idx - 6291456;
    float4 v = *(const float4*)(w_in + j);
    ushort4 h, l;
    h.x = f2bf(v.x); l.x = f2bf(v.x - bf2f(h.x));
    h.y = f2bf(v.y); l.y = f2bf(v.y - bf2f(h.y));
    h.z = f2bf(v.z); l.z = f2bf(v.z - bf2f(h.z));
    h.w = f2bf(v.w); l.w = f2bf(v.w - bf2f(h.w));
    *(ushort4*)(wih + j) = h;
    *(ushort4*)(wil + j) = l;
  } else {
    const int j = idx - 8060928;
    float4 v = *(const float4*)(w_out + j);
    ushort4 h;
    h.x = f2bf(v.x); h.y = f2bf(v.y); h.z = f2bf(v.z); h.w = f2bf(v.w);
    *(ushort4*)(woh + j) = h;
  }
}

// ---------------- MFMA GEMM: C[M,N] = A[M,768] @ B[N,768]^T ----------------
template<int MODE>
__global__ __launch_bounds__(256)
void gemm_mfma(const unsigned short* __restrict__ Ah, const unsigned short* __restrict__ Al,
               const unsigned short* __restrict__ Bh, const unsigned short* __restrict__ Bl,
               float* __restrict__ Cout,
               unsigned short* __restrict__ Qhi, unsigned short* __restrict__ Qlo,
               unsigned short* __restrict__ Khi, unsigned short* __restrict__ Klo,
               unsigned short* __restrict__ Vt)
{
  __shared__ unsigned short Asm[128][64];
  __shared__ unsigned short Bsm[128][64];
  const int t    = threadIdx.x;
  const int lane = t & 63;
  const int wid  = t >> 6;
  const int c    = lane & 15;
  const int g    = lane >> 4;
  const int bn   = blockIdx.x;
  const int bm   = blockIdx.y;
  const int sec    = (MODE == 0) ? (bn / 6) : 0;
  const int nsteps = (MODE == 0 && sec < 2) ? 36 : 12;

  f32x4 acc[4][4];
#pragma unroll
  for (int mi = 0; mi < 4; ++mi)
#pragma unroll
    for (int ni = 0; ni < 4; ++ni) acc[mi][ni] = (f32x4){0.f, 0.f, 0.f, 0.f};

  const size_t Am0 = (size_t)bm * 128;
  const size_t Bn0 = (size_t)bn * 128;
  const int srow = wid * 32 + (lane >> 3);
  const int scol = (lane & 7) * 8;
  const int mh = (wid & 1) * 64;
  const int nh = (wid >> 1) * 64;

  for (int ks = 0; ks < nsteps; ++ks) {
    const int ksec = (ks >= 24) ? 2 : ((ks >= 12) ? 1 : 0);
    const int kin  = (ks - ksec * 12) * 64;
    const unsigned short* Asrc = (ksec == 1) ? Al : Ah;
    const unsigned short* Bsrc = (ksec == 2) ? Bl : Bh;
    __syncthreads();
#pragma unroll
    for (int i = 0; i < 4; ++i) {
      GLD16(Asrc + (Am0 + srow + i * 8) * 768 + kin + scol, &Asm[wid * 32 + i * 8][0]);
      GLD16(Bsrc + (Bn0 + srow + i * 8) * 768 + kin + scol, &Bsm[wid * 32 + i * 8][0]);
    }
    __syncthreads();
#pragma unroll
    for (int kk = 0; kk < 2; ++kk) {
      bf16x8 a[4], bb[4];
#pragma unroll
      for (int mi = 0; mi < 4; ++mi)
        a[mi] = *(const bf16x8*)&Asm[mh + mi * 16 + c][kk * 32 + g * 8];
#pragma unroll
      for (int ni = 0; ni < 4; ++ni)
        bb[ni] = *(const bf16x8*)&Bsm[nh + ni * 16 + c][kk * 32 + g * 8];
#pragma unroll
      for (int mi = 0; mi < 4; ++mi)
#pragma unroll
        for (int ni = 0; ni < 4; ++ni)
          acc[mi][ni] = __builtin_amdgcn_mfma_f32_16x16x32_bf16(a[mi], bb[ni], acc[mi][ni], 0, 0, 0);
    }
  }

  if (MODE == 1) {
#pragma unroll
    for (int mi = 0; mi < 4; ++mi) {
#pragma unroll
      for (int r = 0; r < 4; ++r) {
        const int m = bm * 128 + mh + mi * 16 + g * 4 + r;
#pragma unroll
        for (int ni = 0; ni < 4; ++ni) {
          const int n = bn * 128 + nh + ni * 16 + c;
          Cout[(size_t)m * 768 + n] = acc[mi][ni][r];
        }
      }
    }
  } else {
#pragma unroll
    for (int mi = 0; mi < 4; ++mi) {
#pragma unroll
      for (int r = 0; r < 4; ++r) {
        const int m   = bm * 128 + mh + mi * 16 + g * 4 + r;
        const int bi  = m >> 10;
        const int qi  = m & 1023;
#pragma unroll
        for (int ni = 0; ni < 4; ++ni) {
          const int n  = bn * 128 + nh + ni * 16 + c;
          const int np = n - sec * 768;
          const int h  = np >> 6;
          const int d  = np & 63;
          const size_t bh = (size_t)(bi * 12 + h);
          float v = acc[mi][ni][r];
          if (sec == 0) {
            v *= 0.125f;
            unsigned short hi = f2bf(v);
            Qhi[(bh * 1024 + qi) * 64 + d] = hi;
            Qlo[(bh * 1024 + qi) * 64 + d] = f2bf(v - bf2f(hi));
          } else if (sec == 1) {
            unsigned short hi = f2bf(v);
            Khi[(bh * 1024 + qi) * 64 + d] = hi;
            Klo[(bh * 1024 + qi) * 64 + d] = f2bf(v - bf2f(hi));
          } else {
            Vt[(bh * 64 + d) * 1024 + qi] = f2bf(v);
          }
        }
      }
    }
  }
}

// ---------------- fused MFMA attention + importance ----------------
// 512 threads = 8 waves; wave w owns keys [w*128, w*128+128). 16 waves/CU.
// Uncentered softmax: logits sigma ~0.31 (clamped at 80 as structural guard),
// shift-invariance makes it exact.
struct AttnSmem {
  union {
    unsigned short P[16][1032];
    float AW[8][1032];
  } u;                           // 33,024 B
  float Cpart[8][16][64];        // 32,768 B
  float red[16][8];              // sum-reduce across 8 waves
};

__global__ __launch_bounds__(512, 4)
void attn_mfma(const unsigned short* __restrict__ Qhi, const unsigned short* __restrict__ Qlo,
               const unsigned short* __restrict__ Khi, const unsigned short* __restrict__ Klo,
               const unsigned short* __restrict__ Vt,
               unsigned short* __restrict__ CtxG, float* __restrict__ Imp)
{
  __shared__ AttnSmem sm;
  const int t    = threadIdx.x;
  const int lane = t & 63;
  const int wid  = t >> 6;       // 0..7
  const int g    = lane >> 4;
  const int c    = lane & 15;
  const int b    = blockIdx.x & 7;    // XCD-affinity swizzle
  const int qt   = blockIdx.x >> 3;
  const int q0   = qt * 16;

  float aw[8][4];
#pragma unroll
  for (int kt = 0; kt < 8; ++kt)
#pragma unroll
    for (int r = 0; r < 4; ++r) aw[kt][r] = 0.f;

  for (int h = 0; h < 12; ++h) {
    const size_t bh = (size_t)b * 12 + h;

    const unsigned short* qp_h = Qhi + (bh * 1024 + q0 + c) * 64 + g * 8;
    const unsigned short* qp_l = Qlo + (bh * 1024 + q0 + c) * 64 + g * 8;
    bf16x8 qh0 = *(const bf16x8*)qp_h;
    bf16x8 qh1 = *(const bf16x8*)(qp_h + 32);
    bf16x8 ql0 = *(const bf16x8*)qp_l;
    bf16x8 ql1 = *(const bf16x8*)(qp_l + 32);

    f32x4 acc[8];
#pragma unroll
    for (int kt = 0; kt < 8; ++kt) acc[kt] = (f32x4){0.f, 0.f, 0.f, 0.f};
    const unsigned short* kp_h = Khi + (bh * 1024 + wid * 128 + c) * 64 + g * 8;
    const unsigned short* kp_l = Klo + (bh * 1024 + wid * 128 + c) * 64 + g * 8;
#pragma unroll
    for (int kt = 0; kt < 8; ++kt) {
      const unsigned short* ph = kp_h + kt * 16 * 64;
      const unsigned short* pl = kp_l + kt * 16 * 64;
      bf16x8 kh0 = *(const bf16x8*)ph;
      bf16x8 kh1 = *(const bf16x8*)(ph + 32);
      bf16x8 kl0 = *(const bf16x8*)pl;
      bf16x8 kl1 = *(const bf16x8*)(pl + 32);
      f32x4 a = acc[kt];
      a = __builtin_amdgcn_mfma_f32_16x16x32_bf16(qh0, kh0, a, 0, 0, 0);
      a = __builtin_amdgcn_mfma_f32_16x16x32_bf16(qh1, kh1, a, 0, 0, 0);
      a = __builtin_amdgcn_mfma_f32_16x16x32_bf16(qh0, kl0, a, 0, 0, 0);
      a = __builtin_amdgcn_mfma_f32_16x16x32_bf16(qh1, kl1, a, 0, 0, 0);
      a = __builtin_amdgcn_mfma_f32_16x16x32_bf16(ql0, kh0, a, 0, 0, 0);
      a = __builtin_amdgcn_mfma_f32_16x16x32_bf16(ql1, kh1, a, 0, 0, 0);
      acc[kt] = a;
    }

    // ---- uncentered softmax: exp + cross-wave sum ----
    float sume[4];
#pragma unroll
    for (int r = 0; r < 4; ++r) {
      float s = 0.f;
#pragma unroll
      for (int kt = 0; kt < 8; ++kt) {
        float e = __expf(fminf(acc[kt][r], 80.f));
        acc[kt][r] = e;
        s += e;
      }
      s += __shfl_xor(s, 1);
      s += __shfl_xor(s, 2);
      s += __shfl_xor(s, 4);
      s += __shfl_xor(s, 8);
      sume[r] = s;
    }
    if (c == 0) {
#pragma unroll
      for (int r = 0; r < 4; ++r) sm.red[g * 4 + r][wid] = sume[r];
    }
    __syncthreads();
#pragma unroll
    for (int r = 0; r < 4; ++r) {
      const float* rp = sm.red[g * 4 + r];
      float tot = ((rp[0] + rp[1]) + (rp[2] + rp[3])) +
                  ((rp[4] + rp[5]) + (rp[6] + rp[7]));
      float inv = 1.f / tot;
#pragma unroll
      for (int kt = 0; kt < 8; ++kt) {
        float p = acc[kt][r] * inv;
        aw[kt][r] += p * (1.f / 12.f);
        sm.u.P[g * 4 + r][wid * 128 + kt * 16 + c] = f2bf(p);
      }
    }
    // no barrier: wave reads back only its own P columns below

    // ---- ctx partial: P[16 x 128] @ V^T -> Cpart[wid] ----
    f32x4 cacc[4];
#pragma unroll
    for (int dt = 0; dt < 4; ++dt) cacc[dt] = (f32x4){0.f, 0.f, 0.f, 0.f};
    const unsigned short* vb = Vt + (bh * 64 + c) * 1024 + wid * 128 + g * 8;
#pragma unroll
    for (int ks = 0; ks < 4; ++ks) {
      bf16x8 pf = *(const bf16x8*)&sm.u.P[c][wid * 128 + ks * 32 + g * 8];
#pragma unroll
      for (int dt = 0; dt < 4; ++dt) {
        bf16x8 vf = *(const bf16x8*)(vb + (size_t)dt * 16 * 1024 + ks * 32);
        cacc[dt] = __builtin_amdgcn_mfma_f32_16x16x32_bf16(pf, vf, cacc[dt], 0, 0, 0);
      }
    }
#pragma unroll
    for (int dt = 0; dt < 4; ++dt)
#pragma unroll
      for (int r = 0; r < 4; ++r)
        sm.Cpart[wid][g * 4 + r][dt * 16 + c] = cacc[dt][r];
    __syncthreads();
    for (int i = t; i < 1024; i += 512) {
      int qi = i >> 6, d = i & 63;
      float s = (((sm.Cpart[0][qi][d] + sm.Cpart[1][qi][d]) +
                  (sm.Cpart[2][qi][d] + sm.Cpart[3][qi][d])) +
                 ((sm.Cpart[4][qi][d] + sm.Cpart[5][qi][d]) +
                  (sm.Cpart[6][qi][d] + sm.Cpart[7][qi][d])));
      CtxG[((size_t)(b * 1024 + q0 + qi)) * 768 + h * 64 + d] = f2bf(s);
    }
    __syncthreads();
  }

  // ---- importance from head-mean attention, two 8-row halves ----
  float ia[2] = {0.f, 0.f};
#pragma unroll
  for (int half = 0; half < 2; ++half) {
    if ((g >> 1) == half) {
#pragma unroll
      for (int kt = 0; kt < 8; ++kt)
#pragma unroll
        for (int r = 0; r < 4; ++r)
          sm.u.AW[(g & 1) * 4 + r][wid * 128 + kt * 16 + c] = aw[kt][r];
    }
    __syncthreads();
#pragma unroll
    for (int qi = 0; qi < 8; ++qi) {
#pragma unroll
      for (int cc = 0; cc < 2; ++cc) {
        int k = t * 2 + cc;
        float am = sm.u.AW[qi][k == 0 ? 0 : k - 1];
        float ap = sm.u.AW[qi][k == 1023 ? 1023 : k + 1];
        ia[cc] += fabsf((ap - am) * 0.5f);
      }
    }
    __syncthreads();
  }
#pragma unroll
  for (int cc = 0; cc < 2; ++cc)
    atomicAdd(&Imp[b * 1024 + t * 2 + cc], ia[cc]);
}

// ---------------- conv3 + standardize + softmax(fs/0.1) ----------------
__device__ inline float blk_sum(float v, volatile float* wbuf, int t) {
#pragma unroll
  for (int off = 32; off > 0; off >>= 1) v += __shfl_xor(v, off);
  __syncthreads();
  if ((t & 63) == 0) wbuf[t >> 6] = v;
  __syncthreads();
  return (wbuf[0] + wbuf[1]) + (wbuf[2] + wbuf[3]);
}
__device__ inline float blk_max(float v, volatile float* wbuf, int t) {
#pragma unroll
  for (int off = 32; off > 0; off >>= 1) v = fmaxf(v, __shfl_xor(v, off));
  __syncthreads();
  if ((t & 63) == 0) wbuf[t >> 6] = v;
  __syncthreads();
  return fmaxf(fmaxf(wbuf[0], wbuf[1]), fmaxf(wbuf[2], wbuf[3]));
}

__global__ __launch_bounds__(256)
void scores_kernel(const float* __restrict__ Imp, const float* __restrict__ smw,
                   float* __restrict__ Out)
{
  __shared__ float ip[1026];
  __shared__ float wbuf[4];
  const int b = blockIdx.x;
  const int t = threadIdx.x;

  if (t == 0) { ip[0] = 0.f; ip[1025] = 0.f; }
  float4 iv = *(const float4*)(Imp + (size_t)b * 1024 + t * 4);
  ip[1 + t * 4 + 0] = iv.x;
  ip[1 + t * 4 + 1] = iv.y;
  ip[1 + t * 4 + 2] = iv.z;
  ip[1 + t * 4 + 3] = iv.w;
  __syncthreads();

  const float w0 = smw[0], w1 = smw[1], w2 = smw[2];
  float smv[4];
#pragma unroll
  for (int j = 0; j < 4; ++j) {
    int k = t * 4 + j;
    smv[j] = w0 * ip[k] + w1 * ip[k + 1] + w2 * ip[k + 2];
  }
  float tot = blk_sum((smv[0] + smv[1]) + (smv[2] + smv[3]), wbuf, t);
  float mu  = tot * (1.f / 1024.f);
  float lv = 0.f;
#pragma unroll
  for (int j = 0; j < 4; ++j) { float d = smv[j] - mu; lv += d * d; }
  float var = blk_sum(lv, wbuf, t) * (1.f / 1023.f);
  float inv = 1.f / (sqrtf(var) + 1e-6f);
  float fs[4];
#pragma unroll
  for (int j = 0; j < 4; ++j) fs[j] = (smv[j] - mu) * inv * 10.f;
  float M = blk_max(fmaxf(fmaxf(fs[0], fs[1]), fmaxf(fs[2], fs[3])), wbuf, t);
  float e[4]; float ls = 0.f;
#pragma unroll
  for (int j = 0; j < 4; ++j) { e[j] = __expf(fs[j] - M); ls += e[j]; }
  float S = blk_sum(ls, wbuf, t);
  float r = 1.f / S;
  float4 o = {e[0] * r, e[1] * r, e[2] * r, e[3] * r};
  *(float4*)(Out + (size_t)b * 1024 + t * 4) = o;
}

extern "C" void kernel_launch(void* const* d_in, const int* in_sizes, int n_in,
                              void* d_out, int out_size, void* d_ws, size_t ws_size,
                              hipStream_t stream)
{
  const float* x     = (const float*)d_in[0];
  const float* w_in  = (const float*)d_in[1];
  const float* w_out = (const float*)d_in[2];
  const float* smw   = (const float*)d_in[3];
  float* out = (float*)d_out;

  const size_t SZx  = 6291456;   // 8192*768
  const size_t SZw  = 1769472;   // 2304*768
  const size_t SZwo = 589824;    // 768*768

  unsigned short* xh   = (unsigned short*)d_ws;
  unsigned short* xl   = xh + SZx;
  unsigned short* wih  = xl + SZx;
  unsigned short* wil  = wih + SZw;
  unsigned short* woh  = wil + SZw;
  unsigned short* qhi  = woh + SZwo;
  unsigned short* qlo  = qhi + SZx;
  unsigned short* khi  = qlo + SZx;
  unsigned short* klo  = khi + SZx;
  unsigned short* vt   = klo + SZx;
  unsigned short* ctxb = vt + SZx;
  float* imp = (float*)(ctxb + SZx);

  hipMemsetAsync(imp, 0, BATCH * NSEQ * sizeof(float), stream);

  convert_kernel<<<8448, 256, 0, stream>>>(x, w_in, w_out, xh, xl, wih, wil, woh);
  gemm_mfma<0><<<dim3(18, 64), 256, 0, stream>>>(xh, xl, wih, wil, nullptr,
                                                 qhi, qlo, khi, klo, vt);
  attn_mfma<<<512, 512, 0, stream>>>(qhi, qlo, khi, klo, vt, ctxb, imp);
  gemm_mfma<1><<<dim3(6, 64), 256, 0, stream>>>(ctxb, nullptr, woh, nullptr, out,
                                                nullptr, nullptr, nullptr, nullptr, nullptr);
  scores_kernel<<<8, 256, 0, stream>>>(imp, smw, out + SZx);
}

// Round 6
// 384.336 us; speedup vs baseline: 1.3874x; 1.3874x over previous
//
#include <hip/hip_runtime.h>

#define NSEQ  1024
#define NHEAD 12
#define HDIM  64
#define CDIM  768
#define BATCH 8

typedef short bf16x8 __attribute__((ext_vector_type(8)));
typedef float f32x4  __attribute__((ext_vector_type(4)));

__device__ __forceinline__ float bf2f(unsigned short h) {
  unsigned u = ((unsigned)h) << 16;
  float f;
  __builtin_memcpy(&f, &u, 4);
  return f;
}
__device__ __forceinline__ unsigned short f2bf(float f) {
  unsigned u;
  __builtin_memcpy(&u, &f, 4);
  u = (u + 0x7fffu + ((u >> 16) & 1u)) >> 16;
  return (unsigned short)u;
}

// Fragment-major offsets: every attention-side load = base + lane*8 ushorts (16B).
// Qf/Kf[bh][tile(seq>>4)][ks(d>>5)][lane=g*16+c][j]  (A/B-frag: c=seq&15, g=(d>>3)&3, j=d&7)
__device__ __forceinline__ size_t qk_off(size_t bh, int s, int d) {
  return ((((bh * 64 + (s >> 4)) * 2 + (d >> 5)) * 64) + (((d >> 3) & 3) * 16) + (s & 15)) * 8 + (d & 7);
}
// Vf[bh][dt(d>>4)][ks32(key>>5)][lane=g*16+c][j]  (B-frag: c=d&15, g=(key>>3)&3, j=key&7)
__device__ __forceinline__ size_t v_off(size_t bh, int key, int d) {
  return ((((bh * 4 + (d >> 4)) * 32 + (key >> 5)) * 64) + (((key >> 3) & 3) * 16) + (d & 15)) * 8 + (key & 7);
}

// async global->LDS, 16B per lane; data lands at ldsbase + lane*16
#define GLD16(GP, LP) __builtin_amdgcn_global_load_lds( \
    (const __attribute__((address_space(1))) void*)(GP), \
    (__attribute__((address_space(3))) void*)(LP), 16, 0, 0)

// ---------------- fp32 -> bf16 hi/lo conversion pre-pass ----------------
__global__ __launch_bounds__(256)
void convert_kernel(const float* __restrict__ x, const float* __restrict__ w_in,
                    const float* __restrict__ w_out,
                    unsigned short* __restrict__ xh, unsigned short* __restrict__ xl,
                    unsigned short* __restrict__ wih, unsigned short* __restrict__ wil,
                    unsigned short* __restrict__ woh)
{
  const int idx = (blockIdx.x * 256 + threadIdx.x) * 4;
  if (idx < 6291456) {
    float4 v = *(const float4*)(x + idx);
    ushort4 h, l;
    h.x = f2bf(v.x); l.x = f2bf(v.x - bf2f(h.x));
    h.y = f2bf(v.y); l.y = f2bf(v.y - bf2f(h.y));
    h.z = f2bf(v.z); l.z = f2bf(v.z - bf2f(h.z));
    h.w = f2bf(v.w); l.w = f2bf(v.w - bf2f(h.w));
    *(ushort4*)(xh + idx) = h;
    *(ushort4*)(xl + idx) = l;
  } else if (idx < 6291456 + 1769472) {
    const int j = idx - 6291456;
    float4 v = *(const float4*)(w_in + j);
    ushort4 h, l;
    h.x = f2bf(v.x); l.x = f2bf(v.x - bf2f(h.x));
    h.y = f2bf(v.y); l.y = f2bf(v.y - bf2f(h.y));
    h.z = f2bf(v.z); l.z = f2bf(v.z - bf2f(h.z));
    h.w = f2bf(v.w); l.w = f2bf(v.w - bf2f(h.w));
    *(ushort4*)(wih + j) = h;
    *(ushort4*)(wil + j) = l;
  } else {
    const int j = idx - 8060928;
    float4 v = *(const float4*)(w_out + j);
    ushort4 h;
    h.x = f2bf(v.x); h.y = f2bf(v.y); h.z = f2bf(v.z); h.w = f2bf(v.w);
    *(ushort4*)(woh + j) = h;
  }
}

// ---------------- MFMA GEMM: C[M,N] = A[M,768] @ B[N,768]^T ----------------
// Stacked-K hi/lo: K' = 2304 = [Ah.Bh | Al.Bh | Ah.Bl] -> fp32-grade product.
// MODE 0 epilogue writes q/k/v in MFMA-fragment-major layout.
template<int MODE>
__global__ __launch_bounds__(256)
void gemm_mfma(const unsigned short* __restrict__ Ah, const unsigned short* __restrict__ Al,
               const unsigned short* __restrict__ Bh, const unsigned short* __restrict__ Bl,
               float* __restrict__ Cout,
               unsigned short* __restrict__ Qfh, unsigned short* __restrict__ Qfl,
               unsigned short* __restrict__ Kfh, unsigned short* __restrict__ Kfl,
               unsigned short* __restrict__ Vf)
{
  __shared__ unsigned short Asm[128][64];
  __shared__ unsigned short Bsm[128][64];
  const int t    = threadIdx.x;
  const int lane = t & 63;
  const int wid  = t >> 6;
  const int c    = lane & 15;
  const int g    = lane >> 4;
  const int bn   = blockIdx.x;
  const int bm   = blockIdx.y;
  const int sec    = (MODE == 0) ? (bn / 6) : 0;
  const int nsteps = (MODE == 0 && sec < 2) ? 36 : 12;

  f32x4 acc[4][4];
#pragma unroll
  for (int mi = 0; mi < 4; ++mi)
#pragma unroll
    for (int ni = 0; ni < 4; ++ni) acc[mi][ni] = (f32x4){0.f, 0.f, 0.f, 0.f};

  const size_t Am0 = (size_t)bm * 128;
  const size_t Bn0 = (size_t)bn * 128;
  const int srow = wid * 32 + (lane >> 3);
  const int scol = (lane & 7) * 8;
  const int mh = (wid & 1) * 64;
  const int nh = (wid >> 1) * 64;

  for (int ks = 0; ks < nsteps; ++ks) {
    const int ksec = (ks >= 24) ? 2 : ((ks >= 12) ? 1 : 0);
    const int kin  = (ks - ksec * 12) * 64;
    const unsigned short* Asrc = (ksec == 1) ? Al : Ah;
    const unsigned short* Bsrc = (ksec == 2) ? Bl : Bh;
    __syncthreads();
#pragma unroll
    for (int i = 0; i < 4; ++i) {
      GLD16(Asrc + (Am0 + srow + i * 8) * 768 + kin + scol, &Asm[wid * 32 + i * 8][0]);
      GLD16(Bsrc + (Bn0 + srow + i * 8) * 768 + kin + scol, &Bsm[wid * 32 + i * 8][0]);
    }
    __syncthreads();
#pragma unroll
    for (int kk = 0; kk < 2; ++kk) {
      bf16x8 a[4], bb[4];
#pragma unroll
      for (int mi = 0; mi < 4; ++mi)
        a[mi] = *(const bf16x8*)&Asm[mh + mi * 16 + c][kk * 32 + g * 8];
#pragma unroll
      for (int ni = 0; ni < 4; ++ni)
        bb[ni] = *(const bf16x8*)&Bsm[nh + ni * 16 + c][kk * 32 + g * 8];
#pragma unroll
      for (int mi = 0; mi < 4; ++mi)
#pragma unroll
        for (int ni = 0; ni < 4; ++ni)
          acc[mi][ni] = __builtin_amdgcn_mfma_f32_16x16x32_bf16(a[mi], bb[ni], acc[mi][ni], 0, 0, 0);
    }
  }

  if (MODE == 1) {
#pragma unroll
    for (int mi = 0; mi < 4; ++mi) {
#pragma unroll
      for (int r = 0; r < 4; ++r) {
        const int m = bm * 128 + mh + mi * 16 + g * 4 + r;
#pragma unroll
        for (int ni = 0; ni < 4; ++ni) {
          const int n = bn * 128 + nh + ni * 16 + c;
          Cout[(size_t)m * 768 + n] = acc[mi][ni][r];
        }
      }
    }
  } else {
#pragma unroll
    for (int mi = 0; mi < 4; ++mi) {
#pragma unroll
      for (int r = 0; r < 4; ++r) {
        const int m   = bm * 128 + mh + mi * 16 + g * 4 + r;
        const int bi  = m >> 10;
        const int qi  = m & 1023;    // sequence index
#pragma unroll
        for (int ni = 0; ni < 4; ++ni) {
          const int n  = bn * 128 + nh + ni * 16 + c;
          const int np = n - sec * 768;
          const int h  = np >> 6;
          const int d  = np & 63;
          const size_t bh = (size_t)(bi * 12 + h);
          float v = acc[mi][ni][r];
          if (sec == 0) {
            v *= 0.125f;                      // pre-scale q by 1/sqrt(64)
            size_t off = qk_off(bh, qi, d);
            unsigned short hi = f2bf(v);
            Qfh[off] = hi;
            Qfl[off] = f2bf(v - bf2f(hi));
          } else if (sec == 1) {
            size_t off = qk_off(bh, qi, d);
            unsigned short hi = f2bf(v);
            Kfh[off] = hi;
            Kfl[off] = f2bf(v - bf2f(hi));
          } else {
            Vf[v_off(bh, qi, d)] = f2bf(v);   // qi is the key index here
          }
        }
      }
    }
  }
}

// ---------------- fused MFMA attention + importance ----------------
// 256 threads, 4 waves; wave w owns keys [w*256, w*256+256).
// All Q/K/V loads are fragment-major: base + lane*16B, fully coalesced.
// Uncentered softmax (shift-invariance; clamp 80 structural guard).
struct AttnSmem {
  union {
    unsigned short P[16][1032];
    float AW[8][1032];
  } u;
  float Cpart[4][16][64];
  float red[16][4];
};

__global__ __launch_bounds__(256, 2)
void attn_mfma(const unsigned short* __restrict__ Qfh, const unsigned short* __restrict__ Qfl,
               const unsigned short* __restrict__ Kfh, const unsigned short* __restrict__ Kfl,
               const unsigned short* __restrict__ Vf,
               unsigned short* __restrict__ CtxG, float* __restrict__ Imp)
{
  __shared__ AttnSmem sm;
  const int t    = threadIdx.x;
  const int lane = t & 63;
  const int wid  = t >> 6;
  const int g    = lane >> 4;
  const int c    = lane & 15;
  const int b    = blockIdx.x & 7;    // XCD-affinity swizzle
  const int qt   = blockIdx.x >> 3;
  const int q0   = qt * 16;

  float aw[16][4];
#pragma unroll
  for (int kt = 0; kt < 16; ++kt)
#pragma unroll
    for (int r = 0; r < 4; ++r) aw[kt][r] = 0.f;

  for (int h = 0; h < 12; ++h) {
    const size_t bh = (size_t)b * 12 + h;

    // ---- Q fragments: contiguous ----
    const size_t qbase = ((bh * 64 + qt) * 2) * 512 + lane * 8;
    bf16x8 qh0 = *(const bf16x8*)(Qfh + qbase);
    bf16x8 qh1 = *(const bf16x8*)(Qfh + qbase + 512);
    bf16x8 ql0 = *(const bf16x8*)(Qfl + qbase);
    bf16x8 ql1 = *(const bf16x8*)(Qfl + qbase + 512);

    // ---- S = Q K^T over this wave's 256 keys ----
    f32x4 acc[16];
#pragma unroll
    for (int kt = 0; kt < 16; ++kt) acc[kt] = (f32x4){0.f, 0.f, 0.f, 0.f};
    const size_t kbase = ((bh * 64 + wid * 16) * 2) * 512 + lane * 8;
#pragma unroll
    for (int kt = 0; kt < 16; ++kt) {
      const size_t kb = kbase + (size_t)kt * 1024;
      bf16x8 kh0 = *(const bf16x8*)(Kfh + kb);
      bf16x8 kh1 = *(const bf16x8*)(Kfh + kb + 512);
      bf16x8 kl0 = *(const bf16x8*)(Kfl + kb);
      bf16x8 kl1 = *(const bf16x8*)(Kfl + kb + 512);
      f32x4 a = acc[kt];
      a = __builtin_amdgcn_mfma_f32_16x16x32_bf16(qh0, kh0, a, 0, 0, 0);
      a = __builtin_amdgcn_mfma_f32_16x16x32_bf16(qh1, kh1, a, 0, 0, 0);
      a = __builtin_amdgcn_mfma_f32_16x16x32_bf16(qh0, kl0, a, 0, 0, 0);
      a = __builtin_amdgcn_mfma_f32_16x16x32_bf16(qh1, kl1, a, 0, 0, 0);
      a = __builtin_amdgcn_mfma_f32_16x16x32_bf16(ql0, kh0, a, 0, 0, 0);
      a = __builtin_amdgcn_mfma_f32_16x16x32_bf16(ql1, kh1, a, 0, 0, 0);
      acc[kt] = a;
    }

    // ---- uncentered softmax: exp + cross-wave sum ----
    float sume[4];
#pragma unroll
    for (int r = 0; r < 4; ++r) {
      float s = 0.f;
#pragma unroll
      for (int kt = 0; kt < 16; ++kt) {
        float e = __expf(fminf(acc[kt][r], 80.f));
        acc[kt][r] = e;
        s += e;
      }
      s += __shfl_xor(s, 1);
      s += __shfl_xor(s, 2);
      s += __shfl_xor(s, 4);
      s += __shfl_xor(s, 8);
      sume[r] = s;
    }
    if (c == 0) {
#pragma unroll
      for (int r = 0; r < 4; ++r) sm.red[g * 4 + r][wid] = sume[r];
    }
    __syncthreads();
#pragma unroll
    for (int r = 0; r < 4; ++r) {
      const float* rp = sm.red[g * 4 + r];
      float inv = 1.f / ((rp[0] + rp[1]) + (rp[2] + rp[3]));
#pragma unroll
      for (int kt = 0; kt < 16; ++kt) {
        float p = acc[kt][r] * inv;
        aw[kt][r] += p * (1.f / 12.f);
        sm.u.P[g * 4 + r][wid * 256 + kt * 16 + c] = f2bf(p);
      }
    }
    // no barrier: wave reads back only its own P columns below

    // ---- ctx partial: P[16 x 256] @ V^T ----
    f32x4 cacc[4];
#pragma unroll
    for (int dt = 0; dt < 4; ++dt) cacc[dt] = (f32x4){0.f, 0.f, 0.f, 0.f};
    const size_t vbase = (bh * 4) * 32 * 512 + (size_t)wid * 8 * 512 + lane * 8;
#pragma unroll
    for (int ks = 0; ks < 8; ++ks) {
      bf16x8 pf = *(const bf16x8*)&sm.u.P[c][wid * 256 + ks * 32 + g * 8];
#pragma unroll
      for (int dt = 0; dt < 4; ++dt) {
        bf16x8 vf = *(const bf16x8*)(Vf + vbase + ((size_t)dt * 32 + ks) * 512);
        cacc[dt] = __builtin_amdgcn_mfma_f32_16x16x32_bf16(pf, vf, cacc[dt], 0, 0, 0);
      }
    }
#pragma unroll
    for (int dt = 0; dt < 4; ++dt)
#pragma unroll
      for (int r = 0; r < 4; ++r)
        sm.Cpart[wid][g * 4 + r][dt * 16 + c] = cacc[dt][r];
    __syncthreads();
    for (int i = t; i < 1024; i += 256) {
      int qi = i >> 6, d = i & 63;
      float s = (sm.Cpart[0][qi][d] + sm.Cpart[1][qi][d]) +
                (sm.Cpart[2][qi][d] + sm.Cpart[3][qi][d]);
      CtxG[((size_t)(b * 1024 + q0 + qi)) * 768 + h * 64 + d] = f2bf(s);
    }
    __syncthreads();
  }

  // ---- importance from head-mean attention, two 8-row halves ----
  float ia[4] = {0.f, 0.f, 0.f, 0.f};
#pragma unroll
  for (int half = 0; half < 2; ++half) {
    if ((g >> 1) == half) {
#pragma unroll
      for (int kt = 0; kt < 16; ++kt)
#pragma unroll
        for (int r = 0; r < 4; ++r)
          sm.u.AW[(g & 1) * 4 + r][wid * 256 + kt * 16 + c] = aw[kt][r];
    }
    __syncthreads();
#pragma unroll
    for (int qi = 0; qi < 8; ++qi) {
#pragma unroll
      for (int cc = 0; cc < 4; ++cc) {
        int k = t * 4 + cc;
        float am = sm.u.AW[qi][k == 0 ? 0 : k - 1];
        float ap = sm.u.AW[qi][k == 1023 ? 1023 : k + 1];
        ia[cc] += fabsf((ap - am) * 0.5f);
      }
    }
    __syncthreads();
  }
#pragma unroll
  for (int cc = 0; cc < 4; ++cc)
    atomicAdd(&Imp[b * 1024 + t * 4 + cc], ia[cc]);
}

// ---------------- conv3 + standardize + softmax(fs/0.1) ----------------
__device__ inline float blk_sum(float v, volatile float* wbuf, int t) {
#pragma unroll
  for (int off = 32; off > 0; off >>= 1) v += __shfl_xor(v, off);
  __syncthreads();
  if ((t & 63) == 0) wbuf[t >> 6] = v;
  __syncthreads();
  return (wbuf[0] + wbuf[1]) + (wbuf[2] + wbuf[3]);
}
__device__ inline float blk_max(float v, volatile float* wbuf, int t) {
#pragma unroll
  for (int off = 32; off > 0; off >>= 1) v = fmaxf(v, __shfl_xor(v, off));
  __syncthreads();
  if ((t & 63) == 0) wbuf[t >> 6] = v;
  __syncthreads();
  return fmaxf(fmaxf(wbuf[0], wbuf[1]), fmaxf(wbuf[2], wbuf[3]));
}

__global__ __launch_bounds__(256)
void scores_kernel(const float* __restrict__ Imp, const float* __restrict__ smw,
                   float* __restrict__ Out)
{
  __shared__ float ip[1026];
  __shared__ float wbuf[4];
  const int b = blockIdx.x;
  const int t = threadIdx.x;

  if (t == 0) { ip[0] = 0.f; ip[1025] = 0.f; }
  float4 iv = *(const float4*)(Imp + (size_t)b * 1024 + t * 4);
  ip[1 + t * 4 + 0] = iv.x;
  ip[1 + t * 4 + 1] = iv.y;
  ip[1 + t * 4 + 2] = iv.z;
  ip[1 + t * 4 + 3] = iv.w;
  __syncthreads();

  const float w0 = smw[0], w1 = smw[1], w2 = smw[2];
  float smv[4];
#pragma unroll
  for (int j = 0; j < 4; ++j) {
    int k = t * 4 + j;
    smv[j] = w0 * ip[k] + w1 * ip[k + 1] + w2 * ip[k + 2];
  }
  float tot = blk_sum((smv[0] + smv[1]) + (smv[2] + smv[3]), wbuf, t);
  float mu  = tot * (1.f / 1024.f);
  float lv = 0.f;
#pragma unroll
  for (int j = 0; j < 4; ++j) { float d = smv[j] - mu; lv += d * d; }
  float var = blk_sum(lv, wbuf, t) * (1.f / 1023.f);
  float inv = 1.f / (sqrtf(var) + 1e-6f);
  float fs[4];
#pragma unroll
  for (int j = 0; j < 4; ++j) fs[j] = (smv[j] - mu) * inv * 10.f;
  float M = blk_max(fmaxf(fmaxf(fs[0], fs[1]), fmaxf(fs[2], fs[3])), wbuf, t);
  float e[4]; float ls = 0.f;
#pragma unroll
  for (int j = 0; j < 4; ++j) { e[j] = __expf(fs[j] - M); ls += e[j]; }
  float S = blk_sum(ls, wbuf, t);
  float r = 1.f / S;
  float4 o = {e[0] * r, e[1] * r, e[2] * r, e[3] * r};
  *(float4*)(Out + (size_t)b * 1024 + t * 4) = o;
}

extern "C" void kernel_launch(void* const* d_in, const int* in_sizes, int n_in,
                              void* d_out, int out_size, void* d_ws, size_t ws_size,
                              hipStream_t stream)
{
  const float* x     = (const float*)d_in[0];
  const float* w_in  = (const float*)d_in[1];
  const float* w_out = (const float*)d_in[2];
  const float* smw   = (const float*)d_in[3];
  float* out = (float*)d_out;

  const size_t SZx  = 6291456;   // 8192*768
  const size_t SZw  = 1769472;   // 2304*768
  const size_t SZwo = 589824;    // 768*768

  unsigned short* xh   = (unsigned short*)d_ws;
  unsigned short* xl   = xh + SZx;
  unsigned short* wih  = xl + SZx;
  unsigned short* wil  = wih + SZw;
  unsigned short* woh  = wil + SZw;
  unsigned short* qfh  = woh + SZwo;
  unsigned short* qfl  = qfh + SZx;
  unsigned short* kfh  = qfl + SZx;
  unsigned short* kfl  = kfh + SZx;
  unsigned short* vf   = kfl + SZx;
  unsigned short* ctxb = vf + SZx;
  float* imp = (float*)(ctxb + SZx);

  hipMemsetAsync(imp, 0, BATCH * NSEQ * sizeof(float), stream);

  convert_kernel<<<8448, 256, 0, stream>>>(x, w_in, w_out, xh, xl, wih, wil, woh);
  gemm_mfma<0><<<dim3(18, 64), 256, 0, stream>>>(xh, xl, wih, wil, nullptr,
                                                 qfh, qfl, kfh, kfl, vf);
  attn_mfma<<<512, 256, 0, stream>>>(qfh, qfl, kfh, kfl, vf, ctxb, imp);
  gemm_mfma<1><<<dim3(6, 64), 256, 0, stream>>>(ctxb, nullptr, woh, nullptr, out,
                                                nullptr, nullptr, nullptr, nullptr, nullptr);
  scores_kernel<<<8, 256, 0, stream>>>(imp, smw, out + SZx);
}

// Round 7
// 358.916 us; speedup vs baseline: 1.4857x; 1.0708x over previous
//
#include <hip/hip_runtime.h>

#define NSEQ  1024
#define NHEAD 12
#define HDIM  64
#define CDIM  768
#define BATCH 8

typedef short bf16x8 __attribute__((ext_vector_type(8)));
typedef float f32x4  __attribute__((ext_vector_type(4)));

__device__ __forceinline__ float bf2f(unsigned short h) {
  unsigned u = ((unsigned)h) << 16;
  float f;
  __builtin_memcpy(&f, &u, 4);
  return f;
}
__device__ __forceinline__ unsigned short f2bf(float f) {
  unsigned u;
  __builtin_memcpy(&u, &f, 4);
  u = (u + 0x7fffu + ((u >> 16) & 1u)) >> 16;
  return (unsigned short)u;
}

// Fragment-major offsets: every attention-side load = base + lane*8 ushorts (16B).
__device__ __forceinline__ size_t qk_off(size_t bh, int s, int d) {
  return ((((bh * 64 + (s >> 4)) * 2 + (d >> 5)) * 64) + (((d >> 3) & 3) * 16) + (s & 15)) * 8 + (d & 7);
}
__device__ __forceinline__ size_t v_off(size_t bh, int key, int d) {
  return ((((bh * 4 + (d >> 4)) * 32 + (key >> 5)) * 64) + (((key >> 3) & 3) * 16) + (d & 15)) * 8 + (key & 7);
}

// async global->LDS, 16B per lane; data lands at ldsbase + lane*16
#define GLD16(GP, LP) __builtin_amdgcn_global_load_lds( \
    (const __attribute__((address_space(1))) void*)(GP), \
    (__attribute__((address_space(3))) void*)(LP), 16, 0, 0)

// ---------------- fp32 -> bf16 hi/lo conversion pre-pass ----------------
__global__ __launch_bounds__(256)
void convert_kernel(const float* __restrict__ x, const float* __restrict__ w_in,
                    const float* __restrict__ w_out,
                    unsigned short* __restrict__ xh, unsigned short* __restrict__ xl,
                    unsigned short* __restrict__ wih, unsigned short* __restrict__ wil,
                    unsigned short* __restrict__ woh)
{
  const int idx = (blockIdx.x * 256 + threadIdx.x) * 4;
  if (idx < 6291456) {
    float4 v = *(const float4*)(x + idx);
    ushort4 h, l;
    h.x = f2bf(v.x); l.x = f2bf(v.x - bf2f(h.x));
    h.y = f2bf(v.y); l.y = f2bf(v.y - bf2f(h.y));
    h.z = f2bf(v.z); l.z = f2bf(v.z - bf2f(h.z));
    h.w = f2bf(v.w); l.w = f2bf(v.w - bf2f(h.w));
    *(ushort4*)(xh + idx) = h;
    *(ushort4*)(xl + idx) = l;
  } else if (idx < 6291456 + 1769472) {
    const int j = idx - 6291456;
    float4 v = *(const float4*)(w_in + j);
    ushort4 h, l;
    h.x = f2bf(v.x); l.x = f2bf(v.x - bf2f(h.x));
    h.y = f2bf(v.y); l.y = f2bf(v.y - bf2f(h.y));
    h.z = f2bf(v.z); l.z = f2bf(v.z - bf2f(h.z));
    h.w = f2bf(v.w); l.w = f2bf(v.w - bf2f(h.w));
    *(ushort4*)(wih + j) = h;
    *(ushort4*)(wil + j) = l;
  } else {
    const int j = idx - 8060928;
    float4 v = *(const float4*)(w_out + j);
    ushort4 h;
    h.x = f2bf(v.x); h.y = f2bf(v.y); h.z = f2bf(v.z); h.w = f2bf(v.w);
    *(ushort4*)(woh + j) = h;
  }
}

// ---------------- MFMA GEMM: C[M,N] = A[M,768] @ B[N,768]^T ----------------
// Stacked-K hi/lo: K' = 2304 = [Ah.Bh | Al.Bh | Ah.Bl] -> fp32-grade product.
// XCD-aware 1D grid: xcd = id&7 owns bm band [xcd*8, xcd*8+8); bm_local fast.
// Per-XCD unique A = 3 MB (fits 4 MB L2) instead of full 24 MB.
template<int MODE>
__global__ __launch_bounds__(256)
void gemm_mfma(const unsigned short* __restrict__ Ah, const unsigned short* __restrict__ Al,
               const unsigned short* __restrict__ Bh, const unsigned short* __restrict__ Bl,
               float* __restrict__ Cout,
               unsigned short* __restrict__ Qfh, unsigned short* __restrict__ Qfl,
               unsigned short* __restrict__ Kfh, unsigned short* __restrict__ Kfl,
               unsigned short* __restrict__ Vf)
{
  __shared__ unsigned short Asm[128][64];
  __shared__ unsigned short Bsm[128][64];
  const int t    = threadIdx.x;
  const int lane = t & 63;
  const int wid  = t >> 6;
  const int c    = lane & 15;
  const int g    = lane >> 4;
  const int id   = blockIdx.x;
  const int xcd  = id & 7;
  const int j    = id >> 3;
  const int bm   = (j & 7) + xcd * 8;   // 64 bm rows, 8 per XCD
  const int bn   = j >> 3;              // 18 (MODE 0) or 6 (MODE 1)
  const int sec    = (MODE == 0) ? (bn / 6) : 0;
  const int nsteps = (MODE == 0 && sec < 2) ? 36 : 12;

  f32x4 acc[4][4];
#pragma unroll
  for (int mi = 0; mi < 4; ++mi)
#pragma unroll
    for (int ni = 0; ni < 4; ++ni) acc[mi][ni] = (f32x4){0.f, 0.f, 0.f, 0.f};

  const size_t Am0 = (size_t)bm * 128;
  const size_t Bn0 = (size_t)bn * 128;
  const int srow = wid * 32 + (lane >> 3);
  const int scol = (lane & 7) * 8;
  const int mh = (wid & 1) * 64;
  const int nh = (wid >> 1) * 64;

  for (int ks = 0; ks < nsteps; ++ks) {
    const int ksec = (ks >= 24) ? 2 : ((ks >= 12) ? 1 : 0);
    const int kin  = (ks - ksec * 12) * 64;
    const unsigned short* Asrc = (ksec == 1) ? Al : Ah;
    const unsigned short* Bsrc = (ksec == 2) ? Bl : Bh;
    __syncthreads();
#pragma unroll
    for (int i = 0; i < 4; ++i) {
      GLD16(Asrc + (Am0 + srow + i * 8) * 768 + kin + scol, &Asm[wid * 32 + i * 8][0]);
      GLD16(Bsrc + (Bn0 + srow + i * 8) * 768 + kin + scol, &Bsm[wid * 32 + i * 8][0]);
    }
    __syncthreads();
#pragma unroll
    for (int kk = 0; kk < 2; ++kk) {
      bf16x8 a[4], bb[4];
#pragma unroll
      for (int mi = 0; mi < 4; ++mi)
        a[mi] = *(const bf16x8*)&Asm[mh + mi * 16 + c][kk * 32 + g * 8];
#pragma unroll
      for (int ni = 0; ni < 4; ++ni)
        bb[ni] = *(const bf16x8*)&Bsm[nh + ni * 16 + c][kk * 32 + g * 8];
#pragma unroll
      for (int mi = 0; mi < 4; ++mi)
#pragma unroll
        for (int ni = 0; ni < 4; ++ni)
          acc[mi][ni] = __builtin_amdgcn_mfma_f32_16x16x32_bf16(a[mi], bb[ni], acc[mi][ni], 0, 0, 0);
    }
  }

  if (MODE == 1) {
#pragma unroll
    for (int mi = 0; mi < 4; ++mi) {
#pragma unroll
      for (int r = 0; r < 4; ++r) {
        const int m = bm * 128 + mh + mi * 16 + g * 4 + r;
#pragma unroll
        for (int ni = 0; ni < 4; ++ni) {
          const int n = bn * 128 + nh + ni * 16 + c;
          Cout[(size_t)m * 768 + n] = acc[mi][ni][r];
        }
      }
    }
  } else {
#pragma unroll
    for (int mi = 0; mi < 4; ++mi) {
#pragma unroll
      for (int r = 0; r < 4; ++r) {
        const int m   = bm * 128 + mh + mi * 16 + g * 4 + r;
        const int bi  = m >> 10;
        const int qi  = m & 1023;    // sequence index
#pragma unroll
        for (int ni = 0; ni < 4; ++ni) {
          const int n  = bn * 128 + nh + ni * 16 + c;
          const int np = n - sec * 768;
          const int h  = np >> 6;
          const int d  = np & 63;
          const size_t bh = (size_t)(bi * 12 + h);
          float v = acc[mi][ni][r];
          if (sec == 0) {
            v *= 0.125f;                      // pre-scale q by 1/sqrt(64)
            size_t off = qk_off(bh, qi, d);
            unsigned short hi = f2bf(v);
            Qfh[off] = hi;
            Qfl[off] = f2bf(v - bf2f(hi));
          } else if (sec == 1) {
            size_t off = qk_off(bh, qi, d);
            unsigned short hi = f2bf(v);
            Kfh[off] = hi;
            Kfl[off] = f2bf(v - bf2f(hi));
          } else {
            Vf[v_off(bh, qi, d)] = f2bf(v);   // qi is the key index here
          }
        }
      }
    }
  }
}

// ---------------- fused MFMA attention + importance ----------------
struct AttnSmem {
  union {
    unsigned short P[16][1032];
    float AW[8][1032];
  } u;
  float Cpart[4][16][64];
  float red[16][4];
};

__global__ __launch_bounds__(256, 2)
void attn_mfma(const unsigned short* __restrict__ Qfh, const unsigned short* __restrict__ Qfl,
               const unsigned short* __restrict__ Kfh, const unsigned short* __restrict__ Kfl,
               const unsigned short* __restrict__ Vf,
               unsigned short* __restrict__ CtxG, float* __restrict__ Imp)
{
  __shared__ AttnSmem sm;
  const int t    = threadIdx.x;
  const int lane = t & 63;
  const int wid  = t >> 6;
  const int g    = lane >> 4;
  const int c    = lane & 15;
  const int b    = blockIdx.x & 7;    // XCD-affinity swizzle
  const int qt   = blockIdx.x >> 3;
  const int q0   = qt * 16;

  float aw[16][4];
#pragma unroll
  for (int kt = 0; kt < 16; ++kt)
#pragma unroll
    for (int r = 0; r < 4; ++r) aw[kt][r] = 0.f;

  for (int h = 0; h < 12; ++h) {
    const size_t bh = (size_t)b * 12 + h;

    const size_t qbase = ((bh * 64 + qt) * 2) * 512 + lane * 8;
    bf16x8 qh0 = *(const bf16x8*)(Qfh + qbase);
    bf16x8 qh1 = *(const bf16x8*)(Qfh + qbase + 512);
    bf16x8 ql0 = *(const bf16x8*)(Qfl + qbase);
    bf16x8 ql1 = *(const bf16x8*)(Qfl + qbase + 512);

    f32x4 acc[16];
#pragma unroll
    for (int kt = 0; kt < 16; ++kt) acc[kt] = (f32x4){0.f, 0.f, 0.f, 0.f};
    const size_t kbase = ((bh * 64 + wid * 16) * 2) * 512 + lane * 8;
#pragma unroll
    for (int kt = 0; kt < 16; ++kt) {
      const size_t kb = kbase + (size_t)kt * 1024;
      bf16x8 kh0 = *(const bf16x8*)(Kfh + kb);
      bf16x8 kh1 = *(const bf16x8*)(Kfh + kb + 512);
      bf16x8 kl0 = *(const bf16x8*)(Kfl + kb);
      bf16x8 kl1 = *(const bf16x8*)(Kfl + kb + 512);
      f32x4 a = acc[kt];
      a = __builtin_amdgcn_mfma_f32_16x16x32_bf16(qh0, kh0, a, 0, 0, 0);
      a = __builtin_amdgcn_mfma_f32_16x16x32_bf16(qh1, kh1, a, 0, 0, 0);
      a = __builtin_amdgcn_mfma_f32_16x16x32_bf16(qh0, kl0, a, 0, 0, 0);
      a = __builtin_amdgcn_mfma_f32_16x16x32_bf16(qh1, kl1, a, 0, 0, 0);
      a = __builtin_amdgcn_mfma_f32_16x16x32_bf16(ql0, kh0, a, 0, 0, 0);
      a = __builtin_amdgcn_mfma_f32_16x16x32_bf16(ql1, kh1, a, 0, 0, 0);
      acc[kt] = a;
    }

    float sume[4];
#pragma unroll
    for (int r = 0; r < 4; ++r) {
      float s = 0.f;
#pragma unroll
      for (int kt = 0; kt < 16; ++kt) {
        float e = __expf(fminf(acc[kt][r], 80.f));
        acc[kt][r] = e;
        s += e;
      }
      s += __shfl_xor(s, 1);
      s += __shfl_xor(s, 2);
      s += __shfl_xor(s, 4);
      s += __shfl_xor(s, 8);
      sume[r] = s;
    }
    if (c == 0) {
#pragma unroll
      for (int r = 0; r < 4; ++r) sm.red[g * 4 + r][wid] = sume[r];
    }
    __syncthreads();
#pragma unroll
    for (int r = 0; r < 4; ++r) {
      const float* rp = sm.red[g * 4 + r];
      float inv = 1.f / ((rp[0] + rp[1]) + (rp[2] + rp[3]));
#pragma unroll
      for (int kt = 0; kt < 16; ++kt) {
        float p = acc[kt][r] * inv;
        aw[kt][r] += p * (1.f / 12.f);
        sm.u.P[g * 4 + r][wid * 256 + kt * 16 + c] = f2bf(p);
      }
    }
    // no barrier: wave reads back only its own P columns below

    f32x4 cacc[4];
#pragma unroll
    for (int dt = 0; dt < 4; ++dt) cacc[dt] = (f32x4){0.f, 0.f, 0.f, 0.f};
    const size_t vbase = (bh * 4) * 32 * 512 + (size_t)wid * 8 * 512 + lane * 8;
#pragma unroll
    for (int ks = 0; ks < 8; ++ks) {
      bf16x8 pf = *(const bf16x8*)&sm.u.P[c][wid * 256 + ks * 32 + g * 8];
#pragma unroll
      for (int dt = 0; dt < 4; ++dt) {
        bf16x8 vf = *(const bf16x8*)(Vf + vbase + ((size_t)dt * 32 + ks) * 512);
        cacc[dt] = __builtin_amdgcn_mfma_f32_16x16x32_bf16(pf, vf, cacc[dt], 0, 0, 0);
      }
    }
#pragma unroll
    for (int dt = 0; dt < 4; ++dt)
#pragma unroll
      for (int r = 0; r < 4; ++r)
        sm.Cpart[wid][g * 4 + r][dt * 16 + c] = cacc[dt][r];
    __syncthreads();
    for (int i = t; i < 1024; i += 256) {
      int qi = i >> 6, d = i & 63;
      float s = (sm.Cpart[0][qi][d] + sm.Cpart[1][qi][d]) +
                (sm.Cpart[2][qi][d] + sm.Cpart[3][qi][d]);
      CtxG[((size_t)(b * 1024 + q0 + qi)) * 768 + h * 64 + d] = f2bf(s);
    }
    __syncthreads();
  }

  float ia[4] = {0.f, 0.f, 0.f, 0.f};
#pragma unroll
  for (int half = 0; half < 2; ++half) {
    if ((g >> 1) == half) {
#pragma unroll
      for (int kt = 0; kt < 16; ++kt)
#pragma unroll
        for (int r = 0; r < 4; ++r)
          sm.u.AW[(g & 1) * 4 + r][wid * 256 + kt * 16 + c] = aw[kt][r];
    }
    __syncthreads();
#pragma unroll
    for (int qi = 0; qi < 8; ++qi) {
#pragma unroll
      for (int cc = 0; cc < 4; ++cc) {
        int k = t * 4 + cc;
        float am = sm.u.AW[qi][k == 0 ? 0 : k - 1];
        float ap = sm.u.AW[qi][k == 1023 ? 1023 : k + 1];
        ia[cc] += fabsf((ap - am) * 0.5f);
      }
    }
    __syncthreads();
  }
#pragma unroll
  for (int cc = 0; cc < 4; ++cc)
    atomicAdd(&Imp[b * 1024 + t * 4 + cc], ia[cc]);
}

// ---------------- conv3 + standardize + softmax(fs/0.1) ----------------
__device__ inline float blk_sum(float v, volatile float* wbuf, int t) {
#pragma unroll
  for (int off = 32; off > 0; off >>= 1) v += __shfl_xor(v, off);
  __syncthreads();
  if ((t & 63) == 0) wbuf[t >> 6] = v;
  __syncthreads();
  return (wbuf[0] + wbuf[1]) + (wbuf[2] + wbuf[3]);
}
__device__ inline float blk_max(float v, volatile float* wbuf, int t) {
#pragma unroll
  for (int off = 32; off > 0; off >>= 1) v = fmaxf(v, __shfl_xor(v, off));
  __syncthreads();
  if ((t & 63) == 0) wbuf[t >> 6] = v;
  __syncthreads();
  return fmaxf(fmaxf(wbuf[0], wbuf[1]), fmaxf(wbuf[2], wbuf[3]));
}

__global__ __launch_bounds__(256)
void scores_kernel(const float* __restrict__ Imp, const float* __restrict__ smw,
                   float* __restrict__ Out)
{
  __shared__ float ip[1026];
  __shared__ float wbuf[4];
  const int b = blockIdx.x;
  const int t = threadIdx.x;

  if (t == 0) { ip[0] = 0.f; ip[1025] = 0.f; }
  float4 iv = *(const float4*)(Imp + (size_t)b * 1024 + t * 4);
  ip[1 + t * 4 + 0] = iv.x;
  ip[1 + t * 4 + 1] = iv.y;
  ip[1 + t * 4 + 2] = iv.z;
  ip[1 + t * 4 + 3] = iv.w;
  __syncthreads();

  const float w0 = smw[0], w1 = smw[1], w2 = smw[2];
  float smv[4];
#pragma unroll
  for (int j = 0; j < 4; ++j) {
    int k = t * 4 + j;
    smv[j] = w0 * ip[k] + w1 * ip[k + 1] + w2 * ip[k + 2];
  }
  float tot = blk_sum((smv[0] + smv[1]) + (smv[2] + smv[3]), wbuf, t);
  float mu  = tot * (1.f / 1024.f);
  float lv = 0.f;
#pragma unroll
  for (int j = 0; j < 4; ++j) { float d = smv[j] - mu; lv += d * d; }
  float var = blk_sum(lv, wbuf, t) * (1.f / 1023.f);
  float inv = 1.f / (sqrtf(var) + 1e-6f);
  float fs[4];
#pragma unroll
  for (int j = 0; j < 4; ++j) fs[j] = (smv[j] - mu) * inv * 10.f;
  float M = blk_max(fmaxf(fmaxf(fs[0], fs[1]), fmaxf(fs[2], fs[3])), wbuf, t);
  float e[4]; float ls = 0.f;
#pragma unroll
  for (int j = 0; j < 4; ++j) { e[j] = __expf(fs[j] - M); ls += e[j]; }
  float S = blk_sum(ls, wbuf, t);
  float r = 1.f / S;
  float4 o = {e[0] * r, e[1] * r, e[2] * r, e[3] * r};
  *(float4*)(Out + (size_t)b * 1024 + t * 4) = o;
}

extern "C" void kernel_launch(void* const* d_in, const int* in_sizes, int n_in,
                              void* d_out, int out_size, void* d_ws, size_t ws_size,
                              hipStream_t stream)
{
  const float* x     = (const float*)d_in[0];
  const float* w_in  = (const float*)d_in[1];
  const float* w_out = (const float*)d_in[2];
  const float* smw   = (const float*)d_in[3];
  float* out = (float*)d_out;

  const size_t SZx  = 6291456;   // 8192*768
  const size_t SZw  = 1769472;   // 2304*768
  const size_t SZwo = 589824;    // 768*768

  unsigned short* xh   = (unsigned short*)d_ws;
  unsigned short* xl   = xh + SZx;
  unsigned short* wih  = xl + SZx;
  unsigned short* wil  = wih + SZw;
  unsigned short* woh  = wil + SZw;
  unsigned short* qfh  = woh + SZwo;
  unsigned short* qfl  = qfh + SZx;
  unsigned short* kfh  = qfl + SZx;
  unsigned short* kfl  = kfh + SZx;
  unsigned short* vf   = kfl + SZx;
  unsigned short* ctxb = vf + SZx;
  float* imp = (float*)(ctxb + SZx);

  hipMemsetAsync(imp, 0, BATCH * NSEQ * sizeof(float), stream);

  convert_kernel<<<8448, 256, 0, stream>>>(x, w_in, w_out, xh, xl, wih, wil, woh);
  gemm_mfma<0><<<1152, 256, 0, stream>>>(xh, xl, wih, wil, nullptr,
                                         qfh, qfl, kfh, kfl, vf);
  attn_mfma<<<512, 256, 0, stream>>>(qfh, qfl, kfh, kfl, vf, ctxb, imp);
  gemm_mfma<1><<<384, 256, 0, stream>>>(ctxb, nullptr, woh, nullptr, out,
                                        nullptr, nullptr, nullptr, nullptr, nullptr);
  scores_kernel<<<8, 256, 0, stream>>>(imp, smw, out + SZx);
}